// Round 11
// baseline (8466.669 us; speedup 1.0000x reference)
//
#include <hip/hip_runtime.h>
#include <math.h>

// Problem constants
#define NB 1024      // batch
#define NH 512       // hidden
#define NT 256       // time steps
#define NCD 2        // per-step output dims

typedef unsigned short u16;
typedef __bf16 bf16x8 __attribute__((ext_vector_type(8)));
typedef float  f32x4  __attribute__((ext_vector_type(4)));
typedef unsigned int  u32x4 __attribute__((ext_vector_type(4)));

#define MFMA_BF16 __builtin_amdgcn_mfma_f32_16x16x32_bf16

__device__ __forceinline__ float sigf(float x) { return 1.0f / (1.0f + expf(-x)); }
__device__ __forceinline__ u16 f2b(float f) {   // RTNE
    union { float f; unsigned i; } v; v.f = f;
    unsigned r = v.i + 0x7fffu + ((v.i >> 16) & 1u);
    return (u16)(r >> 16);
}

// async 16B global -> LDS (direct-to-shared DMA); lane L lands at base+L*16.
__device__ __forceinline__ void async_cp16(const void* gptr, void* lptr) {
    __builtin_amdgcn_global_load_lds(
        (const __attribute__((address_space(1))) unsigned int*)gptr,
        (__attribute__((address_space(3))) unsigned int*)lptr,
        16, 0, 0);
}

// agent-scope f32 load (reads of atomically-accumulated out values)
__device__ __forceinline__ float aloadf(const float* p) {
    return __hip_atomic_load((float*)p, __ATOMIC_RELAXED, __HIP_MEMORY_SCOPE_AGENT);
}

// agent-scope 16B load (same-dispatch cross-XCD h traffic; R6-proven)
__device__ __forceinline__ u32x4 aload16(const u16* p) {
    unsigned* q = (unsigned*)(void*)p;
    u32x4 v;
    v.x = __hip_atomic_load(q + 0, __ATOMIC_RELAXED, __HIP_MEMORY_SCOPE_AGENT);
    v.y = __hip_atomic_load(q + 1, __ATOMIC_RELAXED, __HIP_MEMORY_SCOPE_AGENT);
    v.z = __hip_atomic_load(q + 2, __ATOMIC_RELAXED, __HIP_MEMORY_SCOPE_AGENT);
    v.w = __hip_atomic_load(q + 3, __ATOMIC_RELAXED, __HIP_MEMORY_SCOPE_AGENT);
    return v;
}

// ---------------------------------------------------------------------------
__global__ __launch_bounds__(256) void convert3(
    const float* __restrict__ a, const float* __restrict__ b,
    const float* __restrict__ c,
    u16* __restrict__ oa, u16* __restrict__ ob, u16* __restrict__ oc)
{
    const int i = blockIdx.x * 256 + threadIdx.x;   // < 2048*512
    oa[i] = f2b(a[i]); ob[i] = f2b(b[i]); oc[i] = f2b(c[i]);
}

__global__ __launch_bounds__(256) void convw1(
    const float* __restrict__ a, u16* __restrict__ o)
{
    const int i = blockIdx.x * 256 + threadIdx.x;   // < 256*512
    o[i] = f2b(a[i]);
}

__global__ __launch_bounds__(256) void bsum_k(
    const float* __restrict__ bi1, const float* __restrict__ bh1,
    const float* __restrict__ bi2, const float* __restrict__ bh2,
    float* __restrict__ o1, float* __restrict__ o2)
{
    const int i = blockIdx.x * 256 + threadIdx.x;   // < 2048
    o1[i] = bi1[i] + bh1[i];
    o2[i] = bi2[i] + bh2[i];
}

__global__ __launch_bounds__(512) void zero_bar(unsigned* __restrict__ b)
{
    b[threadIdx.x] = 0u;    // 32 grps x 16-word spacing
}

__global__ __launch_bounds__(512) void zero_out(float* __restrict__ o)
{
    o[blockIdx.x * 512 + threadIdx.x] = 0.f;    // NB*NT*NCD = 524288
}

// ---------------------------------------------------------------------------
// init: [h0 | c0] = z @ W_proj^T + b_proj ; h0 (bf16) -> h1,h2 ; c0 (f32)
// ---------------------------------------------------------------------------
__global__ __launch_bounds__(256) void init_kernel(
    const float* __restrict__ zp, const float* __restrict__ zs,
    const float* __restrict__ zst, const float* __restrict__ Wp,
    const float* __restrict__ bp,
    u16* __restrict__ h1, float* __restrict__ c1,
    u16* __restrict__ h2, float* __restrict__ c2)
{
    __shared__ float z[4][256];
    const int tid = threadIdx.x;
    const int b0  = blockIdx.x * 4;
    for (int i = tid; i < 4 * 256; i += 256) {
        const int bb = i >> 8, k = i & 255;
        float v;
        if (k < 64)       v = zp [(b0 + bb) * 64  + k];
        else if (k < 128) v = zs [(b0 + bb) * 64  + (k - 64)];
        else              v = zst[(b0 + bb) * 128 + (k - 128)];
        z[bb][k] = v;
    }
    __syncthreads();
    for (int rt = 0; rt < 4; ++rt) {
        const int r = rt * 256 + tid;          // 0..1023
        const float bias = bp[r];
        float a0 = bias, a1 = bias, a2 = bias, a3 = bias;
        for (int k = 0; k < 256; ++k) {
            const float w = Wp[r * 256 + k];
            a0 += z[0][k] * w; a1 += z[1][k] * w;
            a2 += z[2][k] * w; a3 += z[3][k] * w;
        }
        const float acc[4] = {a0, a1, a2, a3};
        for (int bb = 0; bb < 4; ++bb) {
            const int b = b0 + bb;
            if (r < NH) {
                h1[b * NH + r] = f2b(acc[bb]);
                h2[b * NH + r] = f2b(acc[bb]);
            } else {
                c1[b * NH + r - NH] = acc[bb];
                c2[b * NH + r - NH] = acc[bb];
            }
        }
    }
}

// ---------------------------------------------------------------------------
// R10: ONE kernel per step = R9 kernel1 (pipelined sliced phaseA + lstm1 +
// covered out-barrier) + h1 agent store + barrier#2 ARRIVE + lstm2 with
// REORDERED K (Whh2@h2c macros 0-7, Wih2@h1n macros 8-15; R6-proven
// aload16/vmcnt(6) rotation). Barrier#2 WAIT at m==4, covered by ~5 macros
// of Whh2 work; first h1n touch is the m==5 lookahead aload. Saves one
// dispatch gap per step vs the measured-best 2-dispatch (7120us).
// Counters: bar[grp*16+0] = out-exchange (target 16t);
//           bar[grp*16+8] = h1-exchange (target 16(t+1)). Monotonic.
// ---------------------------------------------------------------------------
__global__ __launch_bounds__(512, 4) void step_fused(
    const u16* __restrict__ h2c,        // h2(t-1); phaseA A-src + lstm2 half1
    const u16* __restrict__ A0,         // h1c
    const u16* __restrict__ W0,         // Whh1 bf16
    const float* __restrict__ bsum1,    // bs1
    const float* __restrict__ Wx,       // Wih1 fp32
    const u16* __restrict__ W1b,        // Wo1 bf16 [256][512]
    const float* __restrict__ bo1, const float* __restrict__ Wo2,
    const float* __restrict__ bo2, float* __restrict__ outp,
    float* __restrict__ c1, u16* __restrict__ h1next,
    const u16* __restrict__ Wih2b, const u16* __restrict__ Whh2b,
    const float* __restrict__ bsum2,
    float* __restrict__ c2, u16* __restrict__ h2next,
    unsigned* __restrict__ bar,
    const int t, const int do_lstm)
{
    __shared__ __align__(16) char smem[61440];   // 3 x (As 4KB | Ws 16KB)
    float* eg  = (float*)smem;                   // lstm epilogue alias

    const int tid  = threadIdx.x;
    const int lane = tid & 63;
    const int wv   = tid >> 6;          // 0..7
    const int g    = wv & 3;            // gate (lstm phases)
    const int mh   = wv >> 2;           // batch half (lstm phases)
    const int l15  = lane & 15;
    const int q    = lane >> 4;         // 0..3
    const int bx   = blockIdx.x;
    const int ut   = (bx & 7) * 2 + ((bx >> 3) & 1);  // 0..15 (XCD-confined W)
    const int grp  = bx >> 4;                          // 0..31
    const int b0   = grp * 32;
    const int u0   = ut * 32;
    const bool has_prev = (t > 0);

    // staging descriptors (R9-verbatim)
    int goffW0, goffW1, goffA = 0, goffWS = 0;
    {
        const int c0 = (wv * 2) * 64 + lane;        // 0..1023
        const int w0r = c0 >> 3;                    // g*32+uu
        goffW0 = ((w0r >> 5) * NH + u0 + (w0r & 31)) * NH + (((c0 & 7) ^ (w0r & 7)) * 8);
        const int c1i = (wv * 2 + 1) * 64 + lane;
        const int w1r = c1i >> 3;
        goffW1 = ((w1r >> 5) * NH + u0 + (w1r & 31)) * NH + (((c1i & 7) ^ (w1r & 7)) * 8);
        if (wv < 4) {
            const int ca = wv * 64 + lane;          // 0..255
            const int ar = ca >> 3;                 // batch row 0..31
            goffA = (b0 + ar) * NH + (((ca & 7) ^ (ar & 7)) * 8);
        }
        if (wv == 4 || wv == 5) {
            const int cs = (wv - 4) * 64 + lane;    // 0..127
            const int rl = cs >> 3;                 // slice row 0..15
            goffWS = (ut * 16 + rl) * NH + (((cs & 7) ^ (rl & 7)) * 8);
        }
    }

    auto issue = [&](int m, int bi) {            // lstm1 staging (W0 + A0)
        const int k0 = (m & 7) * 64;
        char* base = smem + bi * 20480;          // As 4KB | Ws 16KB
        async_cp16((const void*)(W0 + goffW0 + k0),
                   (void*)(base + 4096 + (wv * 2) * 1024));
        async_cp16((const void*)(W0 + goffW1 + k0),
                   (void*)(base + 4096 + (wv * 2 + 1) * 1024));
        if (wv < 4)
            async_cp16((const void*)(A0 + goffA + k0),
                       (void*)(base + wv * 1024));
    };
    auto issueW2 = [&](const u16* Wp, int m, int bi) {   // lstm2 W-only
        const int k0 = (m & 7) * 64;
        char* base = smem + bi * 20480;
        async_cp16((const void*)(Wp + goffW0 + k0), (void*)(base + 4096 + (wv * 2) * 1024));
        async_cp16((const void*)(Wp + goffW1 + k0), (void*)(base + 4096 + (wv * 2 + 1) * 1024));
    };
    auto awrite = [&](char* base, u32x4 v) {     // A-tile LDS write (wv<4)
        *(u32x4*)(base + wv * 1024 + lane * 16) = v;
    };

    // ---- early scalar prefetch (retires during phaseA / early K-loop) ----
    const int u_e  = tid & 31;
    const int bq_e = tid >> 5;          // 0..15
    const int ug_e = u0 + u_e;
    float bs1r[4], bs2r[4], wx0[4], wx1[4], c1pre[2], c2pre[2];
#pragma unroll
    for (int g4 = 0; g4 < 4; ++g4) {
        bs1r[g4] = bsum1[g4 * NH + ug_e];
        bs2r[g4] = bsum2[g4 * NH + ug_e];
        wx0[g4]  = Wx[(g4 * NH + ug_e) * 2 + 0];
        wx1[g4]  = Wx[(g4 * NH + ug_e) * 2 + 1];
    }
    c1pre[0] = c1[(size_t)(b0 + bq_e * 2 + 0) * NH + ug_e];
    c1pre[1] = c1[(size_t)(b0 + bq_e * 2 + 1) * NH + ug_e];
    c2pre[0] = c2[(size_t)(b0 + bq_e * 2 + 0) * NH + ug_e];
    c2pre[1] = c2[(size_t)(b0 + bq_e * 2 + 1) * NH + ug_e];

    // ---- pre-issue lstm1 macro 0 into buf2 (disjoint from phaseA bufs) ---
    if (do_lstm) issue(0, 2);

    // ---------------- phase A: sliced out(t-1), 3-buffer pipelined [R9] ----
    if (has_prev) {
        f32x4 acc_o[2];
        acc_o[0] = (f32x4){0.f, 0.f, 0.f, 0.f};
        acc_o[1] = (f32x4){0.f, 0.f, 0.f, 0.f};

        auto issue_pa = [&](int k, int pb) {
            const int k0 = k * 64;
            char* base = smem + pb * 8192;
            if (wv < 4)
                async_cp16((const void*)(h2c + goffA + k0),
                           (void*)(base + (wv << 10)));
            if (wv == 4 || wv == 5)
                async_cp16((const void*)(W1b + goffWS + k0),
                           (void*)(base + 4096 + ((wv - 4) << 10)));
        };
        issue_pa(0, 0);
        issue_pa(1, 1);
        int cp = 0;
        for (int kk = 0; kk < 8; ++kk) {
            if (kk + 1 < 8)
                asm volatile("s_waitcnt vmcnt(1)" ::: "memory");
            else
                asm volatile("s_waitcnt vmcnt(0)" ::: "memory");
            __builtin_amdgcn_s_barrier();
            if (kk + 2 < 8) {
                int pb = cp + 2; if (pb >= 3) pb -= 3;
                issue_pa(kk + 2, pb);
            }
            const char* pbase = smem + cp * 8192;
#pragma unroll
            for (int kh = 0; kh < 2; ++kh) {
                const int j = (kh * 4 + q) ^ (l15 & 7);
                const bf16x8 bfr = *(const bf16x8*)(pbase + 4096 + l15 * 128 + j * 16);
#pragma unroll
                for (int mi = 0; mi < 2; ++mi) {
                    const bf16x8 av = *(const bf16x8*)(pbase + (mi * 16 + l15) * 128 + j * 16);
                    acc_o[mi] = MFMA_BF16(av, bfr, acc_o[mi], 0, 0, 0);
                }
            }
            ++cp; if (cp == 3) cp = 0;
        }
        const int ng = ut * 16 + l15;
        const float bo1n = bo1[ng];
        const float w20  = Wo2[ng];
        const float w21  = Wo2[256 + ng];
        float pa[2][4], pb[2][4];
#pragma unroll
        for (int mi = 0; mi < 2; ++mi)
#pragma unroll
            for (int r = 0; r < 4; ++r) {
                const float s = fmaxf(acc_o[mi][r] + bo1n, 0.f);
                pa[mi][r] = s * w20;
                pb[mi][r] = s * w21;
            }
#pragma unroll
        for (int off = 1; off < 16; off <<= 1)
#pragma unroll
            for (int mi = 0; mi < 2; ++mi)
#pragma unroll
                for (int r = 0; r < 4; ++r) {
                    pa[mi][r] += __shfl_xor(pa[mi][r], off, 64);
                    pb[mi][r] += __shfl_xor(pb[mi][r], off, 64);
                }
        if (wv == 0 && l15 == 0) {
            const float b20 = (ut == 0) ? bo2[0] : 0.f;
            const float b21 = (ut == 0) ? bo2[1] : 0.f;
#pragma unroll
            for (int mi = 0; mi < 2; ++mi)
#pragma unroll
                for (int r = 0; r < 4; ++r) {
                    const int m = mi * 16 + q * 4 + r;
                    float* dst = outp + (size_t)(b0 + m) * (NT * NCD) + (t - 1) * NCD;
                    atomicAdd(dst + 0, pa[mi][r] + b20);
                    atomicAdd(dst + 1, pb[mi][r] + b21);
                }
        }
        __syncthreads();        // phaseA LDS reads done before buf0/1 reuse
    }
    if (!do_lstm) return;       // final out-only dispatch (t == NT)

    // ---------------- lstm1 K-loop (buf order 2,0,1,...) [R9-verbatim] -----
    f32x4 acc[2];
    acc[0] = (f32x4){0.f, 0.f, 0.f, 0.f};
    acc[1] = (f32x4){0.f, 0.f, 0.f, 0.f};
    {
        const int M = 8;
        issue(1, 0);
        int ci = 2;
        for (int m = 0; m < M; ++m) {
            if (m + 1 < M) {
                if (wv < 4) asm volatile("s_waitcnt vmcnt(3)" ::: "memory");
                else        asm volatile("s_waitcnt vmcnt(2)" ::: "memory");
            } else {
                asm volatile("s_waitcnt vmcnt(0)" ::: "memory");
            }
            __builtin_amdgcn_s_barrier();
            if (m + 2 < M) {
                int bi = ci + 2; if (bi >= 3) bi -= 3;
                issue(m + 2, bi);
            }
            const char* bA = smem + ci * 20480;
            const char* bW = bA + 4096;
#pragma unroll
            for (int khi = 0; khi < 2; ++khi) {
                bf16x8 bfr[2];
#pragma unroll
                for (int ni = 0; ni < 2; ++ni) {
                    const int wrow = g * 32 + ni * 16 + l15;
                    const int j = (khi * 4 + q) ^ (wrow & 7);
                    bfr[ni] = *(const bf16x8*)(bW + wrow * 128 + j * 16);
                }
                const int row = mh * 16 + l15;
                const int j = (khi * 4 + q) ^ (row & 7);
                const bf16x8 av = *(const bf16x8*)(bA + row * 128 + j * 16);
                acc[0] = MFMA_BF16(av, bfr[0], acc[0], 0, 0, 0);
                acc[1] = MFMA_BF16(av, bfr[1], acc[1], 0, 0, 0);
            }
            ++ci; if (ci == 3) ci = 0;
        }
    }

    // ---- barrier#1: out atomicAdds complete; readback x [R9-verbatim] ----
    float r_x[4] = {0.f, 0.f, 0.f, 0.f};
    if (has_prev) {
        unsigned* mybar0 = bar + grp * 16;
        const unsigned target = 16u * (unsigned)t;
        __syncthreads();
        if (tid == 0) {
            __hip_atomic_fetch_add(mybar0, 1u, __ATOMIC_RELAXED, __HIP_MEMORY_SCOPE_AGENT);
            int guard = 0;
            while (__hip_atomic_load(mybar0, __ATOMIC_RELAXED, __HIP_MEMORY_SCOPE_AGENT)
                       < target && ++guard < (1 << 20)) {
                __builtin_amdgcn_s_sleep(1);
            }
        }
        __syncthreads();
#pragma unroll
        for (int jj = 0; jj < 2; ++jj) {
            const float* src = outp + (size_t)(b0 + bq_e * 2 + jj) * (NT * NCD)
                               + (t - 1) * NCD;
            r_x[jj * 2 + 0] = aloadf(src + 0);
            r_x[jj * 2 + 1] = aloadf(src + 1);
        }
    }

    __syncthreads();
    // eg[g][b_local][u_local], stride 33 ; C/D: row=q*4+r, col=l15 [m89]
#pragma unroll
    for (int ni = 0; ni < 2; ++ni)
#pragma unroll
        for (int r = 0; r < 4; ++r)
            eg[(g * 32 + mh * 16 + q * 4 + r) * 33 + ni * 16 + l15] = acc[ni][r];
    __syncthreads();

    // cell1 pointwise; h1 via agent paired store (cross-XCD same-dispatch)
#pragma unroll
    for (int jj = 0; jj < 2; ++jj) {
        const int bl = bq_e * 2 + jj;
        const int b  = b0 + bl;
        float gv[4];
#pragma unroll
        for (int g4 = 0; g4 < 4; ++g4) gv[g4] = eg[(g4 * 32 + bl) * 33 + u_e] + bs1r[g4];
        const float x0 = r_x[jj * 2 + 0];
        const float x1 = r_x[jj * 2 + 1];
#pragma unroll
        for (int g4 = 0; g4 < 4; ++g4) gv[g4] += x0 * wx0[g4] + x1 * wx1[g4];
        const float iv = sigf(gv[0]);
        const float fv = sigf(gv[1]);
        const float gg = tanhf(gv[2]);
        const float ov = sigf(gv[3]);
        const size_t idx = (size_t)b * NH + ug_e;
        const float cn = fv * c1pre[jj] + iv * gg;
        c1[idx] = cn;
        const unsigned hb = (unsigned)f2b(ov * tanhf(cn));
        const unsigned pr = (unsigned)__shfl_xor((int)hb, 1, 64);
        if (!(u_e & 1))
            __hip_atomic_store((unsigned*)(void*)(h1next + idx),
                               hb | (pr << 16),
                               __ATOMIC_RELAXED, __HIP_MEMORY_SCOPE_AGENT);
    }

    // ---- barrier#2 ARRIVE (h1 exchange); wait deferred to lstm2 m==4 -----
    unsigned* mybar1 = bar + grp * 16 + 8;
    const unsigned target1 = 16u * (unsigned)(t + 1);
    __syncthreads();                    // h1 stores drained; eg reads done
    if (tid == 0)
        __hip_atomic_fetch_add(mybar1, 1u, __ATOMIC_RELAXED, __HIP_MEMORY_SCOPE_AGENT);

    // ---------------- lstm2: Whh2@h2c (m 0-7) then Wih2@h1next (m 8-15) ----
    {
        f32x4 acc2[2];
        acc2[0] = (f32x4){0.f, 0.f, 0.f, 0.f};
        acc2[1] = (f32x4){0.f, 0.f, 0.f, 0.f};
        u32x4 rB0, rB1;
        // R6-proven prologue ordering (aload -> W -> aload -> W -> awrites)
        if (wv < 4) rB0 = aload16(h2c + goffA);
        issueW2(Whh2b, 0, 0);
        if (wv < 4) rB1 = aload16(h2c + goffA + 64);
        issueW2(Whh2b, 1, 1);
        if (wv < 4) {
            awrite(smem + 0 * 20480, rB0);
            awrite(smem + 1 * 20480, rB1);      // drains W(0)
            rB0 = aload16(h2c + goffA + 128);
        }
        int ci = 0;
        for (int m = 0; m < 16; ++m) {
            if (m + 1 < 16) {
                if (wv < 4) asm volatile("s_waitcnt vmcnt(6) lgkmcnt(0)" ::: "memory");
                else        asm volatile("s_waitcnt vmcnt(2)" ::: "memory");
            } else {
                asm volatile("s_waitcnt vmcnt(0) lgkmcnt(0)" ::: "memory");
            }
            __builtin_amdgcn_s_barrier();
            if (m == 4) {                       // covered h1-barrier wait:
                if (tid == 0) {                 // first h1n touch is m==5
                    int guard = 0;
                    while (__hip_atomic_load(mybar1, __ATOMIC_RELAXED, __HIP_MEMORY_SCOPE_AGENT)
                               < target1 && ++guard < (1 << 20)) {
                        __builtin_amdgcn_s_sleep(1);
                    }
                }
                __syncthreads();
            }
            if (m + 2 < 16) {
                int bi = ci + 2; if (bi >= 3) bi -= 3;
                if (wv < 4) awrite(smem + bi * 20480, (m & 1) ? rB1 : rB0);
                issueW2((m + 2 < 8) ? Whh2b : Wih2b, m + 2, bi);
                if (wv < 4 && m + 3 < 16) {
                    const u16* Ap = (m + 3 < 8) ? h2c : h1next;
                    const int k0 = ((m + 3) & 7) * 64;
                    if (m & 1) rB0 = aload16(Ap + goffA + k0);
                    else       rB1 = aload16(Ap + goffA + k0);
                }
            }
            const char* bA = smem + ci * 20480;
            const char* bW = bA + 4096;
#pragma unroll
            for (int khi = 0; khi < 2; ++khi) {
                bf16x8 bfr[2];
#pragma unroll
                for (int ni = 0; ni < 2; ++ni) {
                    const int wrow = g * 32 + ni * 16 + l15;
                    const int j = (khi * 4 + q) ^ (wrow & 7);
                    bfr[ni] = *(const bf16x8*)(bW + wrow * 128 + j * 16);
                }
                const int row = mh * 16 + l15;
                const int j = (khi * 4 + q) ^ (row & 7);
                const bf16x8 av = *(const bf16x8*)(bA + row * 128 + j * 16);
                acc2[0] = MFMA_BF16(av, bfr[0], acc2[0], 0, 0, 0);
                acc2[1] = MFMA_BF16(av, bfr[1], acc2[1], 0, 0, 0);
            }
            ++ci; if (ci == 3) ci = 0;
        }

        __syncthreads();
#pragma unroll
        for (int ni = 0; ni < 2; ++ni)
#pragma unroll
            for (int r = 0; r < 4; ++r)
                eg[(g * 32 + mh * 16 + q * 4 + r) * 33 + ni * 16 + l15] = acc2[ni][r];
        __syncthreads();

#pragma unroll
        for (int jj = 0; jj < 2; ++jj) {
            const int bl = bq_e * 2 + jj;
            const int b  = b0 + bl;
            float gv[4];
#pragma unroll
            for (int g4 = 0; g4 < 4; ++g4) gv[g4] = eg[(g4 * 32 + bl) * 33 + u_e] + bs2r[g4];
            const float iv = sigf(gv[0]);
            const float fv = sigf(gv[1]);
            const float gg = tanhf(gv[2]);
            const float ov = sigf(gv[3]);
            const size_t idx = (size_t)b * NH + ug_e;
            const float cn = fv * c2pre[jj] + iv * gg;
            c2[idx] = cn;
            h2next[idx] = f2b(ov * tanhf(cn));   // plain store: next dispatch
        }
    }
}

// ---------------------------------------------------------------------------
extern "C" void kernel_launch(void* const* d_in, const int* in_sizes, int n_in,
                              void* d_out, int out_size, void* d_ws, size_t ws_size,
                              hipStream_t stream)
{
    const float* zp   = (const float*)d_in[0];
    const float* zsk  = (const float*)d_in[1];
    const float* zst  = (const float*)d_in[2];
    const float* Wp   = (const float*)d_in[3];
    const float* bp   = (const float*)d_in[4];
    const float* Wih1 = (const float*)d_in[5];
    const float* Whh1 = (const float*)d_in[6];
    const float* bih1 = (const float*)d_in[7];
    const float* bhh1 = (const float*)d_in[8];
    const float* Wih2 = (const float*)d_in[9];
    const float* Whh2 = (const float*)d_in[10];
    const float* bih2 = (const float*)d_in[11];
    const float* bhh2 = (const float*)d_in[12];
    const float* Wo1  = (const float*)d_in[13];
    const float* bo1  = (const float*)d_in[14];
    const float* Wo2  = (const float*)d_in[15];
    const float* bo2  = (const float*)d_in[16];

    const size_t BH = (size_t)NB * NH;          // 524288
    u16*   h1a   = (u16*)d_ws;
    u16*   h1b   = h1a + BH;
    u16*   h2a   = h1b + BH;
    u16*   h2b   = h2a + BH;
    float* c1    = (float*)(h2b + BH);
    float* c2    = c1 + BH;
    float* bs1   = c2 + BH;                     // 2048
    float* bs2   = bs1 + 2048;                  // 2048
    u16*   Wo1b  = (u16*)(bs2 + 2048);          // 131072 u16 (row-major bf16)
    u16*   Whh1b = Wo1b + 131072;               // 1048576 each
    u16*   Wih2b = Whh1b + 1048576;
    u16*   Whh2b = Wih2b + 1048576;
    unsigned* bar = (unsigned*)(Whh2b + 1048576);   // 512 u32 (32 grps x 16)

    convert3<<<(2048 * 512) / 256, 256, 0, stream>>>(Whh1, Wih2, Whh2, Whh1b, Wih2b, Whh2b);
    convw1<<<(256 * 512) / 256, 256, 0, stream>>>(Wo1, Wo1b);
    bsum_k<<<2048 / 256, 256, 0, stream>>>(bih1, bhh1, bih2, bhh2, bs1, bs2);
    init_kernel<<<NB / 4, 256, 0, stream>>>(zp, zsk, zst, Wp, bp, h1a, c1, h2a, c2);
    zero_bar<<<1, 512, 0, stream>>>(bar);
    zero_out<<<(NB * NT * NCD) / 512, 512, 0, stream>>>((float*)d_out);

    u16* h1c = h1a; u16* h1n = h1b;
    u16* h2c = h2a; u16* h2n = h2b;
    float* outp = (float*)d_out;
    for (int t = 0; t < NT; ++t) {
        step_fused<<<512, 512, 0, stream>>>(
            h2c, h1c, Whh1b, bs1, Wih1,
            Wo1b, bo1, Wo2, bo2, outp, c1, h1n,
            Wih2b, Whh2b, bs2, c2, h2n, bar, t, 1);
        u16* tmp = h1c; h1c = h1n; h1n = tmp;
        tmp = h2c; h2c = h2n; h2n = tmp;
    }
    // final out for t = NT-1 (h2c holds h2(NT-1) after the last swap)
    step_fused<<<512, 512, 0, stream>>>(
        h2c, h1c, Whh1b, bs1, Wih1,
        Wo1b, bo1, Wo2, bo2, outp, c1, h1n,
        Wih2b, Whh2b, bs2, c2, h2n, bar, NT, 0);
}

// Round 12
// 6824.342 us; speedup vs baseline: 1.2407x; 1.2407x over previous
//
#include <hip/hip_runtime.h>
#include <math.h>

// Problem constants
#define NB 1024      // batch
#define NH 512       // hidden
#define NT 256       // time steps
#define NCD 2        // per-step output dims

typedef unsigned short u16;
typedef __bf16 bf16x8 __attribute__((ext_vector_type(8)));
typedef float  f32x4  __attribute__((ext_vector_type(4)));

#define MFMA_BF16 __builtin_amdgcn_mfma_f32_16x16x32_bf16

__device__ __forceinline__ float sigf(float x) { return 1.0f / (1.0f + expf(-x)); }
__device__ __forceinline__ u16 f2b(float f) {   // RTNE
    union { float f; unsigned i; } v; v.f = f;
    unsigned r = v.i + 0x7fffu + ((v.i >> 16) & 1u);
    return (u16)(r >> 16);
}

// async 16B global -> LDS (direct-to-shared DMA); lane L lands at base+L*16.
__device__ __forceinline__ void async_cp16(const void* gptr, void* lptr) {
    __builtin_amdgcn_global_load_lds(
        (const __attribute__((address_space(1))) unsigned int*)gptr,
        (__attribute__((address_space(3))) unsigned int*)lptr,
        16, 0, 0);
}

// agent-scope f32 load (reads of atomically-accumulated out values)
__device__ __forceinline__ float aloadf(const float* p) {
    return __hip_atomic_load((float*)p, __ATOMIC_RELAXED, __HIP_MEMORY_SCOPE_AGENT);
}

// ---------------------------------------------------------------------------
// weight conversion fp32 -> bf16 (three 2048x512 LSTM weights)
// ---------------------------------------------------------------------------
__global__ __launch_bounds__(256) void convert3(
    const float* __restrict__ a, const float* __restrict__ b,
    const float* __restrict__ c,
    u16* __restrict__ oa, u16* __restrict__ ob, u16* __restrict__ oc)
{
    const int i = blockIdx.x * 256 + threadIdx.x;   // < 2048*512
    oa[i] = f2b(a[i]); ob[i] = f2b(b[i]); oc[i] = f2b(c[i]);
}

// Wo1 (256x512) fp32 -> bf16, row-major [n][k]
__global__ __launch_bounds__(256) void convw1(
    const float* __restrict__ a, u16* __restrict__ o)
{
    const int i = blockIdx.x * 256 + threadIdx.x;   // < 256*512
    o[i] = f2b(a[i]);
}

__global__ __launch_bounds__(256) void bsum_k(
    const float* __restrict__ bi1, const float* __restrict__ bh1,
    const float* __restrict__ bi2, const float* __restrict__ bh2,
    float* __restrict__ o1, float* __restrict__ o2)
{
    const int i = blockIdx.x * 256 + threadIdx.x;   // < 2048
    o1[i] = bi1[i] + bh1[i];
    o2[i] = bi2[i] + bh2[i];
}

__global__ __launch_bounds__(512) void zero_bar(unsigned* __restrict__ b)
{
    b[threadIdx.x] = 0u;    // 32 grps x 16-word spacing
}

__global__ __launch_bounds__(512) void zero_out(float* __restrict__ o)
{
    o[blockIdx.x * 512 + threadIdx.x] = 0.f;    // NB*NT*NCD = 524288
}

// ---------------------------------------------------------------------------
// init: [h0 | c0] = z @ W_proj^T + b_proj ; h0 (bf16) -> h1,h2 ; c0 (f32)
// ---------------------------------------------------------------------------
__global__ __launch_bounds__(256) void init_kernel(
    const float* __restrict__ zp, const float* __restrict__ zs,
    const float* __restrict__ zst, const float* __restrict__ Wp,
    const float* __restrict__ bp,
    u16* __restrict__ h1, float* __restrict__ c1,
    u16* __restrict__ h2, float* __restrict__ c2)
{
    __shared__ float z[4][256];
    const int tid = threadIdx.x;
    const int b0  = blockIdx.x * 4;
    for (int i = tid; i < 4 * 256; i += 256) {
        const int bb = i >> 8, k = i & 255;
        float v;
        if (k < 64)       v = zp [(b0 + bb) * 64  + k];
        else if (k < 128) v = zs [(b0 + bb) * 64  + (k - 64)];
        else              v = zst[(b0 + bb) * 128 + (k - 128)];
        z[bb][k] = v;
    }
    __syncthreads();
    for (int rt = 0; rt < 4; ++rt) {
        const int r = rt * 256 + tid;          // 0..1023
        const float bias = bp[r];
        float a0 = bias, a1 = bias, a2 = bias, a3 = bias;
        for (int k = 0; k < 256; ++k) {
            const float w = Wp[r * 256 + k];
            a0 += z[0][k] * w; a1 += z[1][k] * w;
            a2 += z[2][k] * w; a3 += z[3][k] * w;
        }
        const float acc[4] = {a0, a1, a2, a3};
        for (int bb = 0; bb < 4; ++bb) {
            const int b = b0 + bb;
            if (r < NH) {
                h1[b * NH + r] = f2b(acc[bb]);
                h2[b * NH + r] = f2b(acc[bb]);
            } else {
                c1[b * NH + r - NH] = acc[bb];
                c2[b * NH + r - NH] = acc[bb];
            }
        }
    }
}

// ---------------------------------------------------------------------------
// kernel1 (R11): DUAL-PIPE phaseA + lstm1 — the two independent GEMMs share
// one barrier cadence (8 intervals instead of R9's 8+8 serial macros).
//  LDS: lstm ping-pong lb0/lb1 = 2x20KB at [0,40960);
//       phaseA 3x6KB slots at [40960,59392) (A 4KB | Wo1-slice 2KB).
//  Per interval k: wait -> barrier -> issue lstm(k+1)->lb[(k+1)&1] (FIRST)
//  -> issue pa(k+2)->slot[(k+2)%3] (LAST, so counted vmcnt leaves only it)
//  -> compute phaseA macro k + lstm1 macro k.
//  Wait rule (derived per wave class): wv<6 & has_prev & k<7 -> vmcnt(1)
//  (leaves pa(k+1), drains lstm(k)+pa(k)); else vmcnt(0).
//  After loop: phaseA epilogue/atomicAdd -> eg staging (cover) -> out
//  barrier (monotonic 16t) -> x readback -> cell1.  Epilogues R9-verbatim.
// ---------------------------------------------------------------------------
__global__ __launch_bounds__(512, 4) void fused_out_lstm1(
    const u16* __restrict__ h2prev,     // null at t=0 -> skip phaseA (x=0)
    const u16* __restrict__ A0,         // h1c
    const u16* __restrict__ W0,         // Whh1 bf16
    const float* __restrict__ bsum,     // bs1
    const float* __restrict__ Wx,       // Wih1 fp32
    const u16* __restrict__ W1b,        // Wo1 bf16 [256][512]
    const float* __restrict__ bo1, const float* __restrict__ Wo2,
    const float* __restrict__ bo2, float* __restrict__ outp,
    float* __restrict__ c, u16* __restrict__ hnext,
    unsigned* __restrict__ bar,
    const int t, const int do_lstm)
{
    __shared__ __align__(16) char smem[61440];
    float* eg  = (float*)smem;                   // epilogue alias [0,17.5KB)

    const int tid  = threadIdx.x;
    const int lane = tid & 63;
    const int wv   = tid >> 6;          // 0..7
    const int g    = wv & 3;            // gate (lstm1)
    const int mh   = wv >> 2;           // batch half (lstm1)
    const int l15  = lane & 15;
    const int q    = lane >> 4;         // 0..3
    const int bx   = blockIdx.x;
    const int ut   = (bx & 7) * 2 + ((bx >> 3) & 1);  // 0..15
    const int grp  = bx >> 4;                          // 0..31
    const int b0   = grp * 32;
    const int u0   = ut * 32;
    const bool has_prev = (h2prev != 0);

    // staging descriptors (R9-verbatim)
    int goffW0, goffW1, goffA = 0, goffWS = 0;
    {
        const int c0 = (wv * 2) * 64 + lane;        // 0..1023
        const int w0r = c0 >> 3;                    // g*32+uu
        goffW0 = ((w0r >> 5) * NH + u0 + (w0r & 31)) * NH + (((c0 & 7) ^ (w0r & 7)) * 8);
        const int c1i = (wv * 2 + 1) * 64 + lane;
        const int w1r = c1i >> 3;
        goffW1 = ((w1r >> 5) * NH + u0 + (w1r & 31)) * NH + (((c1i & 7) ^ (w1r & 7)) * 8);
        if (wv < 4) {
            const int ca = wv * 64 + lane;          // 0..255
            const int ar = ca >> 3;                 // batch row 0..31
            goffA = (b0 + ar) * NH + (((ca & 7) ^ (ar & 7)) * 8);
        }
        if (wv == 4 || wv == 5) {
            const int cs = (wv - 4) * 64 + lane;    // 0..127
            const int rl = cs >> 3;                 // slice row 0..15
            goffWS = (ut * 16 + rl) * NH + (((cs & 7) ^ (rl & 7)) * 8);
        }
    }

    auto issueL = [&](int m, int s) {            // lstm1 staging -> lb[s]
        const int k0 = (m & 7) * 64;
        char* base = smem + s * 20480;           // As 4KB | Ws 16KB
        async_cp16((const void*)(W0 + goffW0 + k0),
                   (void*)(base + 4096 + (wv * 2) * 1024));
        async_cp16((const void*)(W0 + goffW1 + k0),
                   (void*)(base + 4096 + (wv * 2 + 1) * 1024));
        if (wv < 4)
            async_cp16((const void*)(A0 + goffA + k0),
                       (void*)(base + wv * 1024));
    };
    auto issue_pa = [&](int k, int pb) {         // phaseA staging -> slot pb
        const int k0 = k * 64;
        char* base = smem + 40960 + pb * 6144;   // A 4KB | WS 2KB
        if (wv < 4)
            async_cp16((const void*)(h2prev + goffA + k0),
                       (void*)(base + (wv << 10)));
        if (wv == 4 || wv == 5)
            async_cp16((const void*)(W1b + goffWS + k0),
                       (void*)(base + 4096 + ((wv - 4) << 10)));
    };

    // ---- early scalar prefetch (retires during first intervals) ----------
    const int u_e  = tid & 31;
    const int bq_e = tid >> 5;          // 0..15
    const int ug_e = u0 + u_e;
    float bs[4], wx0[4], wx1[4], cpre[2];
#pragma unroll
    for (int g4 = 0; g4 < 4; ++g4) bs[g4] = bsum[g4 * NH + ug_e];
#pragma unroll
    for (int g4 = 0; g4 < 4; ++g4) {
        wx0[g4] = Wx[(g4 * NH + ug_e) * 2 + 0];
        wx1[g4] = Wx[(g4 * NH + ug_e) * 2 + 1];
    }
    cpre[0] = c[(size_t)(b0 + bq_e * 2 + 0) * NH + ug_e];
    cpre[1] = c[(size_t)(b0 + bq_e * 2 + 1) * NH + ug_e];

    // ---------------- dual-pipe loop: 8 intervals --------------------------
    f32x4 acc_o[2], acc[2];
    acc_o[0] = (f32x4){0.f, 0.f, 0.f, 0.f};
    acc_o[1] = (f32x4){0.f, 0.f, 0.f, 0.f};
    acc[0]   = (f32x4){0.f, 0.f, 0.f, 0.f};
    acc[1]   = (f32x4){0.f, 0.f, 0.f, 0.f};

    // prologue: L0 FIRST, then pa0, pa1 (counted waits leave newest=pa)
    if (do_lstm) issueL(0, 0);
    if (has_prev) { issue_pa(0, 0); issue_pa(1, 1); }

    for (int k = 0; k < 8; ++k) {
        if (has_prev && k < 7 && wv < 6)
            asm volatile("s_waitcnt vmcnt(1)" ::: "memory");
        else
            asm volatile("s_waitcnt vmcnt(0)" ::: "memory");
        __builtin_amdgcn_s_barrier();
        // issue order: lstm first, pa LAST (so vmcnt(1) leaves exactly pa)
        if (do_lstm && k + 1 < 8) issueL(k + 1, (k + 1) & 1);
        if (has_prev && k + 2 < 8) {
            int pb = k + 2; while (pb >= 3) pb -= 3;
            issue_pa(k + 2, pb);
        }
        if (has_prev) {                      // phaseA macro k, slot k%3
            int cp = k; while (cp >= 3) cp -= 3;
            const char* pbase = smem + 40960 + cp * 6144;
#pragma unroll
            for (int kh = 0; kh < 2; ++kh) {
                const int j = (kh * 4 + q) ^ (l15 & 7);
                const bf16x8 bfr = *(const bf16x8*)(pbase + 4096 + l15 * 128 + j * 16);
#pragma unroll
                for (int mi = 0; mi < 2; ++mi) {
                    const bf16x8 av = *(const bf16x8*)(pbase + (mi * 16 + l15) * 128 + j * 16);
                    acc_o[mi] = MFMA_BF16(av, bfr, acc_o[mi], 0, 0, 0);
                }
            }
        }
        if (do_lstm) {                       // lstm1 macro k, slot k&1
            const char* bA = smem + (k & 1) * 20480;
            const char* bW = bA + 4096;
#pragma unroll
            for (int khi = 0; khi < 2; ++khi) {
                bf16x8 bfr[2];
#pragma unroll
                for (int ni = 0; ni < 2; ++ni) {
                    const int wrow = g * 32 + ni * 16 + l15;
                    const int j = (khi * 4 + q) ^ (wrow & 7);
                    bfr[ni] = *(const bf16x8*)(bW + wrow * 128 + j * 16);
                }
                const int row = mh * 16 + l15;
                const int j = (khi * 4 + q) ^ (row & 7);
                const bf16x8 av = *(const bf16x8*)(bA + row * 128 + j * 16);
                acc[0] = MFMA_BF16(av, bfr[0], acc[0], 0, 0, 0);
                acc[1] = MFMA_BF16(av, bfr[1], acc[1], 0, 0, 0);
            }
        }
    }

    // ---------------- phaseA epilogue (register-only -> atomicAdd) ---------
    if (has_prev) {
        const int ng = ut * 16 + l15;
        const float bo1n = bo1[ng];
        const float w20  = Wo2[ng];
        const float w21  = Wo2[256 + ng];
        float pa[2][4], pb[2][4];
#pragma unroll
        for (int mi = 0; mi < 2; ++mi)
#pragma unroll
            for (int r = 0; r < 4; ++r) {
                const float s = fmaxf(acc_o[mi][r] + bo1n, 0.f);
                pa[mi][r] = s * w20;
                pb[mi][r] = s * w21;
            }
#pragma unroll
        for (int off = 1; off < 16; off <<= 1)
#pragma unroll
            for (int mi = 0; mi < 2; ++mi)
#pragma unroll
                for (int r = 0; r < 4; ++r) {
                    pa[mi][r] += __shfl_xor(pa[mi][r], off, 64);
                    pb[mi][r] += __shfl_xor(pb[mi][r], off, 64);
                }
        if (wv == 0 && l15 == 0) {
            const float b20 = (ut == 0) ? bo2[0] : 0.f;
            const float b21 = (ut == 0) ? bo2[1] : 0.f;
#pragma unroll
            for (int mi = 0; mi < 2; ++mi)
#pragma unroll
                for (int r = 0; r < 4; ++r) {
                    const int m = mi * 16 + q * 4 + r;
                    float* dst = outp + (size_t)(b0 + m) * (NT * NCD) + (t - 1) * NCD;
                    atomicAdd(dst + 0, pa[mi][r] + b20);
                    atomicAdd(dst + 1, pb[mi][r] + b21);
                }
        }
    }
    if (!do_lstm) return;       // final out-only dispatch (t == NT)

    // ---- stage lstm1 acc into eg (also covers atomicAdd completion) ------
    __syncthreads();            // all LDS buffer reads done (incl. DMA drained)
#pragma unroll
    for (int ni = 0; ni < 2; ++ni)
#pragma unroll
        for (int r = 0; r < 4; ++r)
            eg[(g * 32 + mh * 16 + q * 4 + r) * 33 + ni * 16 + l15] = acc[ni][r];
    __syncthreads();

    // ---- per-grp barrier: all 16 blocks' out-atomicAdds complete ----------
    float r_x[4] = {0.f, 0.f, 0.f, 0.f};
    if (has_prev) {
        unsigned* mybar = bar + grp * 16;       // 64B spacing per grp
        const unsigned target = 16u * (unsigned)t;   // monotonic, t>=1
        if (tid == 0) {
            __hip_atomic_fetch_add(mybar, 1u, __ATOMIC_RELAXED, __HIP_MEMORY_SCOPE_AGENT);
            int guard = 0;
            while (__hip_atomic_load(mybar, __ATOMIC_RELAXED, __HIP_MEMORY_SCOPE_AGENT)
                       < target && ++guard < (1 << 20)) {
                __builtin_amdgcn_s_sleep(1);
            }
        }
        __syncthreads();
        // x = out(t-1) for own rows (agent loads; includes bo2 from ut==0)
#pragma unroll
        for (int jj = 0; jj < 2; ++jj) {
            const float* src = outp + (size_t)(b0 + bq_e * 2 + jj) * (NT * NCD)
                               + (t - 1) * NCD;
            r_x[jj * 2 + 0] = aloadf(src + 0);
            r_x[jj * 2 + 1] = aloadf(src + 1);
        }
    }

    // fused pointwise cell update (scalars prefetched at kernel start)
#pragma unroll
    for (int jj = 0; jj < 2; ++jj) {
        const int bl = bq_e * 2 + jj;
        const int b  = b0 + bl;
        float gv[4];
#pragma unroll
        for (int g4 = 0; g4 < 4; ++g4) gv[g4] = eg[(g4 * 32 + bl) * 33 + u_e] + bs[g4];
        const float x0 = r_x[jj * 2 + 0];
        const float x1 = r_x[jj * 2 + 1];
#pragma unroll
        for (int g4 = 0; g4 < 4; ++g4) gv[g4] += x0 * wx0[g4] + x1 * wx1[g4];
        const float iv = sigf(gv[0]);
        const float fv = sigf(gv[1]);
        const float gg = tanhf(gv[2]);
        const float ov = sigf(gv[3]);
        const size_t idx = (size_t)b * NH + ug_e;
        const float cn = fv * cpre[jj] + iv * gg;
        c[idx] = cn;
        hnext[idx] = f2b(ov * tanhf(cn));   // plain store: next-dispatch reader
    }
}

// ---------------------------------------------------------------------------
// LSTM2: R14-verbatim (measured) kernel with scalar prefetch (npass=2).
// ---------------------------------------------------------------------------
__global__ __launch_bounds__(512, 4) void lstm_mfma32(
    const u16* __restrict__ A0, const u16* __restrict__ W0,
    const u16* __restrict__ A1, const u16* __restrict__ W1,
    const float* __restrict__ bsum,
    float* __restrict__ c, u16* __restrict__ hnext,
    const int npass)
{
    __shared__ __align__(16) char smem[61440];
    float* eg = (float*)smem;

    const int tid  = threadIdx.x;
    const int lane = tid & 63;
    const int wv   = tid >> 6;
    const int g    = wv & 3;
    const int mh   = wv >> 2;
    const int l15  = lane & 15;
    const int q    = lane >> 4;
    const int bx   = blockIdx.x;
    const int ut   = (bx & 7) * 2 + ((bx >> 3) & 1);
    const int grp  = bx >> 4;
    const int b0   = grp * 32;
    const int u0   = ut * 32;

    int goffW0, goffW1, goffA = 0;
    {
        const int c0 = (wv * 2) * 64 + lane;
        const int w0r = c0 >> 3;
        goffW0 = ((w0r >> 5) * NH + u0 + (w0r & 31)) * NH + (((c0 & 7) ^ (w0r & 7)) * 8);
        const int c1i = (wv * 2 + 1) * 64 + lane;
        const int w1r = c1i >> 3;
        goffW1 = ((w1r >> 5) * NH + u0 + (w1r & 31)) * NH + (((c1i & 7) ^ (w1r & 7)) * 8);
        if (wv < 4) {
            const int ca = wv * 64 + lane;
            const int ar = ca >> 3;
            goffA = (b0 + ar) * NH + (((ca & 7) ^ (ar & 7)) * 8);
        }
    }

    // early scalar prefetch (retires alongside macro-0's loads)
    const int u_e  = tid & 31;
    const int bq_e = tid >> 5;
    const int ug_e = u0 + u_e;
    float bs[4], cpre[2];
#pragma unroll
    for (int g4 = 0; g4 < 4; ++g4) bs[g4] = bsum[g4 * NH + ug_e];
    cpre[0] = c[(size_t)(b0 + bq_e * 2 + 0) * NH + ug_e];
    cpre[1] = c[(size_t)(b0 + bq_e * 2 + 1) * NH + ug_e];

    f32x4 acc[2];
    acc[0] = (f32x4){0.f, 0.f, 0.f, 0.f};
    acc[1] = (f32x4){0.f, 0.f, 0.f, 0.f};

    const int M = npass * 8;

    auto issue = [&](int m, int bi) {
        const u16* __restrict__ Ap = (m < 8) ? A0 : A1;
        const u16* __restrict__ Wp = (m < 8) ? W0 : W1;
        const int k0 = (m & 7) * 64;
        char* base = smem + bi * 20480;
        async_cp16((const void*)(Wp + goffW0 + k0),
                   (void*)(base + 4096 + (wv * 2) * 1024));
        async_cp16((const void*)(Wp + goffW1 + k0),
                   (void*)(base + 4096 + (wv * 2 + 1) * 1024));
        if (wv < 4)
            async_cp16((const void*)(Ap + goffA + k0),
                       (void*)(base + wv * 1024));
    };

    issue(0, 0);
    if (M > 1) issue(1, 1);
    int ci = 0;
    for (int m = 0; m < M; ++m) {
        if (m + 1 < M) {
            if (wv < 4) asm volatile("s_waitcnt vmcnt(3)" ::: "memory");
            else        asm volatile("s_waitcnt vmcnt(2)" ::: "memory");
        } else {
            asm volatile("s_waitcnt vmcnt(0)" ::: "memory");
        }
        __builtin_amdgcn_s_barrier();
        if (m + 2 < M) {
            int bi = ci + 2; if (bi >= 3) bi -= 3;
            issue(m + 2, bi);
        }
        const char* bA = smem + ci * 20480;
        const char* bW = bA + 4096;
#pragma unroll
        for (int khi = 0; khi < 2; ++khi) {
            bf16x8 bfr[2];
#pragma unroll
            for (int ni = 0; ni < 2; ++ni) {
                const int wrow = g * 32 + ni * 16 + l15;
                const int j = (khi * 4 + q) ^ (wrow & 7);
                bfr[ni] = *(const bf16x8*)(bW + wrow * 128 + j * 16);
            }
            const int row = mh * 16 + l15;
            const int j = (khi * 4 + q) ^ (row & 7);
            const bf16x8 av = *(const bf16x8*)(bA + row * 128 + j * 16);
            acc[0] = MFMA_BF16(av, bfr[0], acc[0], 0, 0, 0);
            acc[1] = MFMA_BF16(av, bfr[1], acc[1], 0, 0, 0);
        }
        ++ci; if (ci == 3) ci = 0;
    }

    __syncthreads();
#pragma unroll
    for (int ni = 0; ni < 2; ++ni)
#pragma unroll
        for (int r = 0; r < 4; ++r)
            eg[(g * 32 + mh * 16 + q * 4 + r) * 33 + ni * 16 + l15] = acc[ni][r];
    __syncthreads();

#pragma unroll
    for (int jj = 0; jj < 2; ++jj) {
        const int bl = bq_e * 2 + jj;
        const int b  = b0 + bl;
        float gv[4];
#pragma unroll
        for (int g4 = 0; g4 < 4; ++g4) gv[g4] = eg[(g4 * 32 + bl) * 33 + u_e] + bs[g4];
        const float iv = sigf(gv[0]);
        const float fv = sigf(gv[1]);
        const float gg = tanhf(gv[2]);
        const float ov = sigf(gv[3]);
        const size_t idx = (size_t)b * NH + ug_e;
        const float cn = fv * cpre[jj] + iv * gg;
        c[idx] = cn;
        hnext[idx] = f2b(ov * tanhf(cn));
    }
}

// ---------------------------------------------------------------------------
extern "C" void kernel_launch(void* const* d_in, const int* in_sizes, int n_in,
                              void* d_out, int out_size, void* d_ws, size_t ws_size,
                              hipStream_t stream)
{
    const float* zp   = (const float*)d_in[0];
    const float* zsk  = (const float*)d_in[1];
    const float* zst  = (const float*)d_in[2];
    const float* Wp   = (const float*)d_in[3];
    const float* bp   = (const float*)d_in[4];
    const float* Wih1 = (const float*)d_in[5];
    const float* Whh1 = (const float*)d_in[6];
    const float* bih1 = (const float*)d_in[7];
    const float* bhh1 = (const float*)d_in[8];
    const float* Wih2 = (const float*)d_in[9];
    const float* Whh2 = (const float*)d_in[10];
    const float* bih2 = (const float*)d_in[11];
    const float* bhh2 = (const float*)d_in[12];
    const float* Wo1  = (const float*)d_in[13];
    const float* bo1  = (const float*)d_in[14];
    const float* Wo2  = (const float*)d_in[15];
    const float* bo2  = (const float*)d_in[16];

    const size_t BH = (size_t)NB * NH;          // 524288
    u16*   h1a   = (u16*)d_ws;
    u16*   h1b   = h1a + BH;
    u16*   h2a   = h1b + BH;
    u16*   h2b   = h2a + BH;
    float* c1    = (float*)(h2b + BH);
    float* c2    = c1 + BH;
    float* bs1   = c2 + BH;                     // 2048
    float* bs2   = bs1 + 2048;                  // 2048
    u16*   Wo1b  = (u16*)(bs2 + 2048);          // 131072 u16 (row-major bf16)
    u16*   Whh1b = Wo1b + 131072;               // 1048576 each
    u16*   Wih2b = Whh1b + 1048576;
    u16*   Whh2b = Wih2b + 1048576;
    unsigned* bar = (unsigned*)(Whh2b + 1048576);   // 512 u32 (32 grps x 16)

    convert3<<<(2048 * 512) / 256, 256, 0, stream>>>(Whh1, Wih2, Whh2, Whh1b, Wih2b, Whh2b);
    convw1<<<(256 * 512) / 256, 256, 0, stream>>>(Wo1, Wo1b);
    bsum_k<<<2048 / 256, 256, 0, stream>>>(bih1, bhh1, bih2, bhh2, bs1, bs2);
    init_kernel<<<NB / 4, 256, 0, stream>>>(zp, zsk, zst, Wp, bp, h1a, c1, h2a, c2);
    zero_bar<<<1, 512, 0, stream>>>(bar);
    zero_out<<<(NB * NT * NCD) / 512, 512, 0, stream>>>((float*)d_out);

    u16* h1c = h1a; u16* h1n = h1b;
    u16* h2c = h2a; u16* h2n = h2b;
    float* outp = (float*)d_out;
    for (int t = 0; t < NT; ++t) {
        fused_out_lstm1<<<512, 512, 0, stream>>>(
            (t == 0) ? (const u16*)0 : h2c, h1c, Whh1b, bs1, Wih1,
            Wo1b, bo1, Wo2, bo2, outp, c1, h1n, bar, t, 1);
        lstm_mfma32<<<512, 512, 0, stream>>>(h1n, Wih2b, h2c, Whh2b,
                                             bs2, c2, h2n, 2);
        u16* tmp = h1c; h1c = h1n; h1n = tmp;
        tmp = h2c; h2c = h2n; h2n = tmp;
    }
    // final out for t = NT-1 (h2c holds h2(NT-1) after the last swap)
    fused_out_lstm1<<<512, 512, 0, stream>>>(
        h2c, h1c, Whh1b, bs1, Wih1,
        Wo1b, bo1, Wo2, bo2, outp, c1, h1n, bar, NT, 0);
}